// Round 13
// baseline (180.673 us; speedup 1.0000x reference)
//
#include <hip/hip_runtime.h>

#define BIGV 1e10f
constexpr float INV_LN2 = 1.4426950408889634f;
constexpr float LN2f    = 0.6931471805599453f;

// ---------------- Phase 1: ND[b][r][e] f16, stride 516 elems ----------------
// Row r holds nd(r,jy) = -|x_r - y_jy|^2/ln2 at elem e = jy + (r&3); e outside
// [r&3, 511+(r&3)] = -60000 guards (r11/r12-proven, absmax 0.0).
__global__ __launch_bounds__(256) void dist_kernel(
    const float* __restrict__ X, const float* __restrict__ Y,
    unsigned short* __restrict__ ND)
{
  const int b  = blockIdx.x;
  const int jg = blockIdx.y;            // 8 j-groups of 64
  const int t  = threadIdx.x;
  const int wv = t >> 6, lane = t & 63;
  const int jy = 64 * jg + lane;

  __shared__ float4 xsh4[2048];         // x rows, 32 KB
  __shared__ float  x2sh[512];

  const float*  xb  = X + (size_t)b * 8192;
  const float4* xb4 = (const float4*)xb;
  const float*  yb  = Y + (size_t)b * 8192;

  for (int i = t; i < 2048; i += 256) xsh4[i] = xb4[i];

  {
    const float4* p = (const float4*)(xb + (size_t)(2 * t) * 16);
    float4 a0=p[0],a1=p[1],a2=p[2],a3=p[3], c0=p[4],c1=p[5],c2=p[6],c3=p[7];
    float sa = 0.f, sc = 0.f;
    sa=fmaf(a0.x,a0.x,sa); sa=fmaf(a0.y,a0.y,sa); sa=fmaf(a0.z,a0.z,sa); sa=fmaf(a0.w,a0.w,sa);
    sa=fmaf(a1.x,a1.x,sa); sa=fmaf(a1.y,a1.y,sa); sa=fmaf(a1.z,a1.z,sa); sa=fmaf(a1.w,a1.w,sa);
    sa=fmaf(a2.x,a2.x,sa); sa=fmaf(a2.y,a2.y,sa); sa=fmaf(a2.z,a2.z,sa); sa=fmaf(a2.w,a2.w,sa);
    sa=fmaf(a3.x,a3.x,sa); sa=fmaf(a3.y,a3.y,sa); sa=fmaf(a3.z,a3.z,sa); sa=fmaf(a3.w,a3.w,sa);
    sc=fmaf(c0.x,c0.x,sc); sc=fmaf(c0.y,c0.y,sc); sc=fmaf(c0.z,c0.z,sc); sc=fmaf(c0.w,c0.w,sc);
    sc=fmaf(c1.x,c1.x,sc); sc=fmaf(c1.y,c1.y,sc); sc=fmaf(c1.z,c1.z,sc); sc=fmaf(c1.w,c1.w,sc);
    sc=fmaf(c2.x,c2.x,sc); sc=fmaf(c2.y,c2.y,sc); sc=fmaf(c2.z,c2.z,sc); sc=fmaf(c2.w,c2.w,sc);
    sc=fmaf(c3.x,c3.x,sc); sc=fmaf(c3.y,c3.y,sc); sc=fmaf(c3.z,c3.z,sc); sc=fmaf(c3.w,c3.w,sc);
    x2sh[2 * t] = sa; x2sh[2 * t + 1] = sc;
  }

  float yv[16]; float y2 = 0.f;
  {
    const float4* p = (const float4*)(yb + (size_t)jy * 16);
    float4 v0 = p[0], v1 = p[1], v2 = p[2], v3 = p[3];
    yv[0]=v0.x; yv[1]=v0.y; yv[2]=v0.z; yv[3]=v0.w;
    yv[4]=v1.x; yv[5]=v1.y; yv[6]=v1.z; yv[7]=v1.w;
    yv[8]=v2.x; yv[9]=v2.y; yv[10]=v2.z; yv[11]=v2.w;
    yv[12]=v3.x; yv[13]=v3.y; yv[14]=v3.z; yv[15]=v3.w;
    #pragma unroll
    for (int q = 0; q < 16; ++q) y2 = fmaf(yv[q], yv[q], y2);
  }
  __syncthreads();

  unsigned short* nb = ND + (size_t)b * 512 * 516;

  for (int rr = 0; rr < 128; rr += 2) {
    const int r = 128 * wv + rr;
    const float4* xr4 = &xsh4[(size_t)r * 4];
    float4 a0 = xr4[0], a1 = xr4[1], a2 = xr4[2], a3 = xr4[3];
    float4 c0 = xr4[4], c1 = xr4[5], c2 = xr4[6], c3 = xr4[7];
    float xa[16] = { a0.x,a0.y,a0.z,a0.w, a1.x,a1.y,a1.z,a1.w,
                     a2.x,a2.y,a2.z,a2.w, a3.x,a3.y,a3.z,a3.w };
    float xc[16] = { c0.x,c0.y,c0.z,c0.w, c1.x,c1.y,c1.z,c1.w,
                     c2.x,c2.y,c2.z,c2.w, c3.x,c3.y,c3.z,c3.w };
    float d0 = 0.f, d1 = 0.f;
    #pragma unroll
    for (int q = 0; q < 16; ++q) {
      d0 = fmaf(xa[q], yv[q], d0);
      d1 = fmaf(xc[q], yv[q], d1);
    }
    const float nd0 = (2.f * d0 - x2sh[r]     - y2) * INV_LN2;
    const float nd1 = (2.f * d1 - x2sh[r + 1] - y2) * INV_LN2;
    nb[(size_t)r * 516 + jy + (r & 3)]             = __builtin_bit_cast(unsigned short, (_Float16)nd0);
    nb[(size_t)(r + 1) * 516 + jy + ((r + 1) & 3)] = __builtin_bit_cast(unsigned short, (_Float16)nd1);
  }

  if (jg == 0) {
    const unsigned short G = __builtin_bit_cast(unsigned short, (_Float16)(-60000.0f));
    #pragma unroll
    for (int rr2 = 0; rr2 < 2; ++rr2) {
      const int r = 2 * t + rr2, sh = r & 3;
      unsigned short* rowp = nb + (size_t)r * 516;
      #pragma unroll
      for (int k = 0; k < 4; ++k) {
        const int e = (k < sh) ? k : 512 + k;
        rowp[e] = G;
      }
    }
  }
}

// ---------------- Phase 2: log2-domain DP, TWO batches per 1024-thread block ----------------
// Half h = tid>>9 runs batch 2*blockIdx+h with the r10-proven 8-wave schedule:
// wave w (= (tid>>6)&7) owns rows 64w+1..64w+64, lane l row 64w+l+1, col
// j = t-l; DPP wf_sr1 cross-lane; per-half LDS ring, lag-5 phases of K=16;
// guarded edge phases; 15-step peel; lgkm-only barrier. 4 waves/SIMD = two
// independent softmin chains per SIMD -> second batch fills the stalls.
template<bool PRE>
__global__ __launch_bounds__(1024, 1) void dp_kernel(
    const unsigned short* __restrict__ ND, const float* __restrict__ X,
    const float* __restrict__ Y, float* __restrict__ out)
{
  const int tid = threadIdx.x;
  const int h   = tid >> 9;
  const int b   = 2 * blockIdx.x + h;
  const int w   = (tid >> 6) & 7;
  const int l   = tid & 63;
  const int r   = 64 * w + l;

  __shared__ alignas(16) float ring[2][7][64];

  float P  = BIGV;
  float dg = (w == 0 && l == 0) ? 0.f : BIGV;
  const bool doring = (l == 63) && (w < 7);
  const int  lq = l >> 2;

  const uint2* rp = nullptr;
  uint2 cur0, cur1, cur2, cur3, nxt0, nxt1, nxt2, nxt3;
  float xr0[16];
  float x2 = 0.f;
  const float4* yb4 = (const float4*)(Y + (size_t)b * 8192);

  if constexpr (PRE) {
    rp = (const uint2*)(ND + ((size_t)b * 512 + (size_t)r) * 516);
    cur0 = rp[min(max(0 - lq, 0), 128)];
    cur1 = rp[min(max(1 - lq, 0), 128)];
    cur2 = rp[min(max(2 - lq, 0), 128)];
    cur3 = rp[min(max(3 - lq, 0), 128)];
  } else {
    const float4* px = (const float4*)(X + ((size_t)b * 512 + r) * 16);
    float4 u0 = px[0], u1 = px[1], u2 = px[2], u3 = px[3];
    float tv[16] = { u0.x,u0.y,u0.z,u0.w, u1.x,u1.y,u1.z,u1.w,
                     u2.x,u2.y,u2.z,u2.w, u3.x,u3.y,u3.z,u3.w };
    #pragma unroll
    for (int q = 0; q < 16; ++q) { xr0[q] = tv[q]; x2 = fmaf(tv[q], tv[q], x2); }
  }

#define DPSTEP(K, DW, HI, RV, GUARDED)                                         \
  {                                                                            \
    float nd_;                                                                 \
    if constexpr (PRE) {                                                       \
      nd_ = (float)__builtin_bit_cast(_Float16,                                \
              (unsigned short)((HI) ? ((DW) >> 16) : ((DW) & 0xffffu)));       \
    } else {                                                                   \
      const int jy_ = tml + (K);                                               \
      const int jc_ = min(max(jy_, 0), 511);                                   \
      float4 q0 = yb4[4*jc_+0], q1 = yb4[4*jc_+1],                             \
             q2 = yb4[4*jc_+2], q3 = yb4[4*jc_+3];                             \
      float yv_[16] = { q0.x,q0.y,q0.z,q0.w, q1.x,q1.y,q1.z,q1.w,              \
                        q2.x,q2.y,q2.z,q2.w, q3.x,q3.y,q3.z,q3.w };            \
      float y2_ = 0.f, d0_ = 0.f;                                              \
      _Pragma("unroll")                                                        \
      for (int q = 0; q < 16; ++q) {                                           \
        y2_ = fmaf(yv_[q], yv_[q], y2_);                                       \
        d0_ = fmaf(xr0[q], yv_[q], d0_);                                       \
      }                                                                        \
      nd_ = (2.f * d0_ - x2 - y2_) * INV_LN2;                                  \
    }                                                                          \
    const int sp_ = __builtin_amdgcn_update_dpp(__builtin_bit_cast(int, P),    \
        __builtin_bit_cast(int, P), 0x138, 0xF, 0xF, false);                   \
    float up_ = __builtin_bit_cast(float, sp_);                                \
    if (l == 0) up_ = (w == 0) ? BIGV : (RV);                                  \
    const float mn_ = fminf(fminf(dg, up_), P);                                \
    const float s_  = __builtin_amdgcn_exp2f(mn_ - dg)                         \
                    + __builtin_amdgcn_exp2f(mn_ - up_)                        \
                    + __builtin_amdgcn_exp2f(mn_ - P);                         \
    float c_ = mn_ - __builtin_amdgcn_logf(s_) - nd_;                          \
    if (GUARDED) c_ = ((unsigned)(tml + (K)) < 512u) ? c_ : BIGV;              \
    dg = up_; P = c_;                                                          \
    if (doring) ring[h][w][(tb64 + (K)) & 63] = c_;                            \
  }

#define DP16(G)                                                                \
    DPSTEP(0,  cur0.x, 0, rg0.x, G) DPSTEP(1,  cur0.x, 1, rg0.y, G)            \
    DPSTEP(2,  cur0.y, 0, rg0.z, G) DPSTEP(3,  cur0.y, 1, rg0.w, G)            \
    DPSTEP(4,  cur1.x, 0, rg1.x, G) DPSTEP(5,  cur1.x, 1, rg1.y, G)            \
    DPSTEP(6,  cur1.y, 0, rg1.z, G) DPSTEP(7,  cur1.y, 1, rg1.w, G)            \
    DPSTEP(8,  cur2.x, 0, rg2.x, G) DPSTEP(9,  cur2.x, 1, rg2.y, G)            \
    DPSTEP(10, cur2.y, 0, rg2.z, G) DPSTEP(11, cur2.y, 1, rg2.w, G)            \
    DPSTEP(12, cur3.x, 0, rg3.x, G) DPSTEP(13, cur3.x, 1, rg3.y, G)            \
    DPSTEP(14, cur3.y, 0, rg3.z, G) DPSTEP(15, cur3.y, 1, rg3.w, G)

  for (int p = 0; p < 70; ++p) {
    const int pw = p - 5 * w;
    if ((unsigned)pw < 36u) {
      const int tb   = 16 * pw + 1;
      const int tml  = tb - l - 1;
      const int tb64 = tb - 64;
      const int wi   = (w > 0) ? (w - 1) : 0;
      const float4* rpq = (const float4*)(&ring[h][wi][0]);
      const int rb = 4 * (pw & 3);
      const float4 rg0 = rpq[rb], rg1 = rpq[rb+1], rg2 = rpq[rb+2], rg3 = rpq[rb+3];
      if constexpr (PRE) {
        const int gb = 4 * pw + 4;
        nxt0 = rp[min(max(gb + 0 - lq, 0), 128)];
        nxt1 = rp[min(max(gb + 1 - lq, 0), 128)];
        nxt2 = rp[min(max(gb + 2 - lq, 0), 128)];
        nxt3 = rp[min(max(gb + 3 - lq, 0), 128)];
      }
      if ((unsigned)(pw - 4) < 28u) {
        DP16(false)
      } else {
        DP16(true)
      }
      if constexpr (PRE) { cur0 = nxt0; cur1 = nxt1; cur2 = nxt2; cur3 = nxt3; }
    }
    __builtin_amdgcn_sched_barrier(0);
    asm volatile("s_waitcnt lgkmcnt(0)" ::: "memory");
    __builtin_amdgcn_s_barrier();
    __builtin_amdgcn_sched_barrier(0);
  }

  // peel: each half's wave 7, pw = 35 (tb = 561), steps 561..575 (skip 576)
  if (w == 7) {
    const int tb   = 561;
    const int tml  = tb - l - 1;
    const int tb64 = tb - 64;
    const float4* rpq = (const float4*)(&ring[h][6][0]);
    const int rb = 4 * (35 & 3);
    const float4 rg0 = rpq[rb], rg1 = rpq[rb+1], rg2 = rpq[rb+2], rg3 = rpq[rb+3];
    DPSTEP(0,  cur0.x, 0, rg0.x, true) DPSTEP(1,  cur0.x, 1, rg0.y, true)
    DPSTEP(2,  cur0.y, 0, rg0.z, true) DPSTEP(3,  cur0.y, 1, rg0.w, true)
    DPSTEP(4,  cur1.x, 0, rg1.x, true) DPSTEP(5,  cur1.x, 1, rg1.y, true)
    DPSTEP(6,  cur1.y, 0, rg1.z, true) DPSTEP(7,  cur1.y, 1, rg1.w, true)
    DPSTEP(8,  cur2.x, 0, rg2.x, true) DPSTEP(9,  cur2.x, 1, rg2.y, true)
    DPSTEP(10, cur2.y, 0, rg2.z, true) DPSTEP(11, cur2.y, 1, rg2.w, true)
    DPSTEP(12, cur3.x, 0, rg3.x, true) DPSTEP(13, cur3.x, 1, rg3.y, true)
    DPSTEP(14, cur3.y, 0, rg3.z, true)
  }
#undef DP16
#undef DPSTEP

  if (w == 7 && l == 63) out[b] = P * LN2f;   // P = r'(512,512) in log2 units
}

extern "C" void kernel_launch(void* const* d_in, const int* in_sizes, int n_in,
                              void* d_out, int out_size, void* d_ws, size_t ws_size,
                              hipStream_t stream)
{
  const float* x = (const float*)d_in[0];
  const float* y = (const float*)d_in[1];
  float* o = (float*)d_out;
  const size_t need = (size_t)64 * 512 * 516 * 2;   // 33,816,576 B
  if (ws_size >= need) {
    unsigned short* nd = (unsigned short*)d_ws;
    dist_kernel<<<dim3(64, 8), 256, 0, stream>>>(x, y, nd);
    dp_kernel<true><<<32, 1024, 0, stream>>>(nd, x, y, o);
  } else {
    dp_kernel<false><<<32, 1024, 0, stream>>>(nullptr, x, y, o);
  }
}

// Round 14
// 121.223 us; speedup vs baseline: 1.4904x; 1.4904x over previous
//
#include <hip/hip_runtime.h>

#define BIGV 1e10f
constexpr float INV_LN2 = 1.4426950408889634f;
constexpr float LN2f    = 0.6931471805599453f;

// ---------------- Phase 1: ND[b][r][e] f16, stride 516 elems (r11/r12-proven) ----------------
// Row r holds nd(r,jy) = -|x_r - y_jy|^2/ln2 at elem e = jy + (r&3); e outside
// [r&3, 511+(r&3)] = -60000 guards.
__global__ __launch_bounds__(256) void dist_kernel(
    const float* __restrict__ X, const float* __restrict__ Y,
    unsigned short* __restrict__ ND)
{
  const int b  = blockIdx.x;
  const int jg = blockIdx.y;            // 8 j-groups of 64
  const int t  = threadIdx.x;
  const int wv = t >> 6, lane = t & 63;
  const int jy = 64 * jg + lane;

  __shared__ float4 xsh4[2048];         // x rows, 32 KB
  __shared__ float  x2sh[512];

  const float*  xb  = X + (size_t)b * 8192;
  const float4* xb4 = (const float4*)xb;
  const float*  yb  = Y + (size_t)b * 8192;

  for (int i = t; i < 2048; i += 256) xsh4[i] = xb4[i];

  {
    const float4* p = (const float4*)(xb + (size_t)(2 * t) * 16);
    float4 a0=p[0],a1=p[1],a2=p[2],a3=p[3], c0=p[4],c1=p[5],c2=p[6],c3=p[7];
    float sa = 0.f, sc = 0.f;
    sa=fmaf(a0.x,a0.x,sa); sa=fmaf(a0.y,a0.y,sa); sa=fmaf(a0.z,a0.z,sa); sa=fmaf(a0.w,a0.w,sa);
    sa=fmaf(a1.x,a1.x,sa); sa=fmaf(a1.y,a1.y,sa); sa=fmaf(a1.z,a1.z,sa); sa=fmaf(a1.w,a1.w,sa);
    sa=fmaf(a2.x,a2.x,sa); sa=fmaf(a2.y,a2.y,sa); sa=fmaf(a2.z,a2.z,sa); sa=fmaf(a2.w,a2.w,sa);
    sa=fmaf(a3.x,a3.x,sa); sa=fmaf(a3.y,a3.y,sa); sa=fmaf(a3.z,a3.z,sa); sa=fmaf(a3.w,a3.w,sa);
    sc=fmaf(c0.x,c0.x,sc); sc=fmaf(c0.y,c0.y,sc); sc=fmaf(c0.z,c0.z,sc); sc=fmaf(c0.w,c0.w,sc);
    sc=fmaf(c1.x,c1.x,sc); sc=fmaf(c1.y,c1.y,sc); sc=fmaf(c1.z,c1.z,sc); sc=fmaf(c1.w,c1.w,sc);
    sc=fmaf(c2.x,c2.x,sc); sc=fmaf(c2.y,c2.y,sc); sc=fmaf(c2.z,c2.z,sc); sc=fmaf(c2.w,c2.w,sc);
    sc=fmaf(c3.x,c3.x,sc); sc=fmaf(c3.y,c3.y,sc); sc=fmaf(c3.z,c3.z,sc); sc=fmaf(c3.w,c3.w,sc);
    x2sh[2 * t] = sa; x2sh[2 * t + 1] = sc;
  }

  float yv[16]; float y2 = 0.f;
  {
    const float4* p = (const float4*)(yb + (size_t)jy * 16);
    float4 v0 = p[0], v1 = p[1], v2 = p[2], v3 = p[3];
    yv[0]=v0.x; yv[1]=v0.y; yv[2]=v0.z; yv[3]=v0.w;
    yv[4]=v1.x; yv[5]=v1.y; yv[6]=v1.z; yv[7]=v1.w;
    yv[8]=v2.x; yv[9]=v2.y; yv[10]=v2.z; yv[11]=v2.w;
    yv[12]=v3.x; yv[13]=v3.y; yv[14]=v3.z; yv[15]=v3.w;
    #pragma unroll
    for (int q = 0; q < 16; ++q) y2 = fmaf(yv[q], yv[q], y2);
  }
  __syncthreads();

  unsigned short* nb = ND + (size_t)b * 512 * 516;

  for (int rr = 0; rr < 128; rr += 2) {
    const int r = 128 * wv + rr;
    const float4* xr4 = &xsh4[(size_t)r * 4];
    float4 a0 = xr4[0], a1 = xr4[1], a2 = xr4[2], a3 = xr4[3];
    float4 c0 = xr4[4], c1 = xr4[5], c2 = xr4[6], c3 = xr4[7];
    float xa[16] = { a0.x,a0.y,a0.z,a0.w, a1.x,a1.y,a1.z,a1.w,
                     a2.x,a2.y,a2.z,a2.w, a3.x,a3.y,a3.z,a3.w };
    float xc[16] = { c0.x,c0.y,c0.z,c0.w, c1.x,c1.y,c1.z,c1.w,
                     c2.x,c2.y,c2.z,c2.w, c3.x,c3.y,c3.z,c3.w };
    float d0 = 0.f, d1 = 0.f;
    #pragma unroll
    for (int q = 0; q < 16; ++q) {
      d0 = fmaf(xa[q], yv[q], d0);
      d1 = fmaf(xc[q], yv[q], d1);
    }
    const float nd0 = (2.f * d0 - x2sh[r]     - y2) * INV_LN2;
    const float nd1 = (2.f * d1 - x2sh[r + 1] - y2) * INV_LN2;
    nb[(size_t)r * 516 + jy + (r & 3)]             = __builtin_bit_cast(unsigned short, (_Float16)nd0);
    nb[(size_t)(r + 1) * 516 + jy + ((r + 1) & 3)] = __builtin_bit_cast(unsigned short, (_Float16)nd1);
  }

  if (jg == 0) {
    const unsigned short G = __builtin_bit_cast(unsigned short, (_Float16)(-60000.0f));
    #pragma unroll
    for (int rr2 = 0; rr2 < 2; ++rr2) {
      const int r = 2 * t + rr2, sh = r & 3;
      unsigned short* rowp = nb + (size_t)r * 516;
      #pragma unroll
      for (int k = 0; k < 4; ++k) {
        const int e = (k < sh) ? k : 512 + k;
        rowp[e] = G;
      }
    }
  }
}

// ---------------- Phase 2: log2-domain wavefront DP, 8-wave pipeline (r10-proven) ----------------
// Wave w owns DP rows 64w+1..64w+64; lane l owns row r+1 (r = 64w+l).
// Step t: lane l at col j = t-l. Cross-lane: DPP wf_sr1 of P (dg = prev up).
// Cross-wave: ring[w][64] in LDS, lag 5 phases of K=16. 2 waves/SIMD fill
// dependency stalls. nd streamed as aligned uint2 / 4 steps; lgkm-only barrier.
template<bool PRE>
__global__ __launch_bounds__(512, 1) void dp_kernel(
    const unsigned short* __restrict__ ND, const float* __restrict__ X,
    const float* __restrict__ Y, float* __restrict__ out)
{
  const int b   = blockIdx.x;
  const int tid = threadIdx.x;
  const int w   = tid >> 6;
  const int l   = tid & 63;
  const int r   = 64 * w + l;

  __shared__ alignas(16) float ring[8][64];   // rows 0..6 = boundaries, 7 = dump

  float P  = BIGV;
  float dg = (w == 0 && l == 0) ? 0.f : BIGV;
  const bool doring = (l == 63) && (w < 7);
  const int  lq = l >> 2;

  const uint2* rp = nullptr;
  uint2 cur0, cur1, cur2, cur3, nxt0, nxt1, nxt2, nxt3;
  float xr0[16];
  float x2 = 0.f;
  const float4* yb4 = (const float4*)(Y + (size_t)b * 8192);

  if constexpr (PRE) {
    rp = (const uint2*)(ND + ((size_t)b * 512 + (size_t)r) * 516);
    cur0 = rp[min(max(0 - lq, 0), 128)];
    cur1 = rp[min(max(1 - lq, 0), 128)];
    cur2 = rp[min(max(2 - lq, 0), 128)];
    cur3 = rp[min(max(3 - lq, 0), 128)];
  } else {
    const float4* px = (const float4*)(X + ((size_t)b * 512 + r) * 16);
    float4 u0 = px[0], u1 = px[1], u2 = px[2], u3 = px[3];
    float tv[16] = { u0.x,u0.y,u0.z,u0.w, u1.x,u1.y,u1.z,u1.w,
                     u2.x,u2.y,u2.z,u2.w, u3.x,u3.y,u3.z,u3.w };
    #pragma unroll
    for (int q = 0; q < 16; ++q) { xr0[q] = tv[q]; x2 = fmaf(tv[q], tv[q], x2); }
  }

#define DPSTEP(K, DW, HI, RV, GUARDED)                                         \
  {                                                                            \
    float nd_;                                                                 \
    if constexpr (PRE) {                                                       \
      nd_ = (float)__builtin_bit_cast(_Float16,                                \
              (unsigned short)((HI) ? ((DW) >> 16) : ((DW) & 0xffffu)));       \
    } else {                                                                   \
      const int jy_ = tml + (K);                                               \
      const int jc_ = min(max(jy_, 0), 511);                                   \
      float4 q0 = yb4[4*jc_+0], q1 = yb4[4*jc_+1],                             \
             q2 = yb4[4*jc_+2], q3 = yb4[4*jc_+3];                             \
      float yv_[16] = { q0.x,q0.y,q0.z,q0.w, q1.x,q1.y,q1.z,q1.w,              \
                        q2.x,q2.y,q2.z,q2.w, q3.x,q3.y,q3.z,q3.w };            \
      float y2_ = 0.f, d0_ = 0.f;                                              \
      _Pragma("unroll")                                                        \
      for (int q = 0; q < 16; ++q) {                                           \
        y2_ = fmaf(yv_[q], yv_[q], y2_);                                       \
        d0_ = fmaf(xr0[q], yv_[q], d0_);                                       \
      }                                                                        \
      nd_ = (2.f * d0_ - x2 - y2_) * INV_LN2;                                  \
    }                                                                          \
    const int sp_ = __builtin_amdgcn_update_dpp(__builtin_bit_cast(int, P),    \
        __builtin_bit_cast(int, P), 0x138, 0xF, 0xF, false);                   \
    float up_ = __builtin_bit_cast(float, sp_);                                \
    if (l == 0) up_ = (w == 0) ? BIGV : (RV);                                  \
    const float mn_ = fminf(fminf(dg, up_), P);                                \
    const float s_  = __builtin_amdgcn_exp2f(mn_ - dg)                         \
                    + __builtin_amdgcn_exp2f(mn_ - up_)                        \
                    + __builtin_amdgcn_exp2f(mn_ - P);                         \
    float c_ = mn_ - __builtin_amdgcn_logf(s_) - nd_;                          \
    if (GUARDED) c_ = ((unsigned)(tml + (K)) < 512u) ? c_ : BIGV;              \
    dg = up_; P = c_;                                                          \
    if (doring) ring[w][(tb64 + (K)) & 63] = c_;                               \
  }

#define DP16(G)                                                                \
    DPSTEP(0,  cur0.x, 0, rg0.x, G) DPSTEP(1,  cur0.x, 1, rg0.y, G)            \
    DPSTEP(2,  cur0.y, 0, rg0.z, G) DPSTEP(3,  cur0.y, 1, rg0.w, G)            \
    DPSTEP(4,  cur1.x, 0, rg1.x, G) DPSTEP(5,  cur1.x, 1, rg1.y, G)            \
    DPSTEP(6,  cur1.y, 0, rg1.z, G) DPSTEP(7,  cur1.y, 1, rg1.w, G)            \
    DPSTEP(8,  cur2.x, 0, rg2.x, G) DPSTEP(9,  cur2.x, 1, rg2.y, G)            \
    DPSTEP(10, cur2.y, 0, rg2.z, G) DPSTEP(11, cur2.y, 1, rg2.w, G)            \
    DPSTEP(12, cur3.x, 0, rg3.x, G) DPSTEP(13, cur3.x, 1, rg3.y, G)            \
    DPSTEP(14, cur3.y, 0, rg3.z, G) DPSTEP(15, cur3.y, 1, rg3.w, G)

  for (int p = 0; p < 70; ++p) {
    const int pw = p - 5 * w;
    if ((unsigned)pw < 36u) {
      const int tb   = 16 * pw + 1;
      const int tml  = tb - l - 1;
      const int tb64 = tb - 64;
      const int wi   = (w > 0) ? (w - 1) : 0;
      const float4* rpq = (const float4*)(&ring[wi][0]);
      const int rb = 4 * (pw & 3);
      const float4 rg0 = rpq[rb], rg1 = rpq[rb+1], rg2 = rpq[rb+2], rg3 = rpq[rb+3];
      if constexpr (PRE) {
        const int gb = 4 * pw + 4;
        nxt0 = rp[min(max(gb + 0 - lq, 0), 128)];
        nxt1 = rp[min(max(gb + 1 - lq, 0), 128)];
        nxt2 = rp[min(max(gb + 2 - lq, 0), 128)];
        nxt3 = rp[min(max(gb + 3 - lq, 0), 128)];
      }
      if ((unsigned)(pw - 4) < 28u) {
        DP16(false)
      } else {
        DP16(true)
      }
      if constexpr (PRE) { cur0 = nxt0; cur1 = nxt1; cur2 = nxt2; cur3 = nxt3; }
    }
    __builtin_amdgcn_sched_barrier(0);
    asm volatile("s_waitcnt lgkmcnt(0)" ::: "memory");
    __builtin_amdgcn_s_barrier();
    __builtin_amdgcn_sched_barrier(0);
  }

  // peel: wave 7's pw = 35 (tb = 561), steps t = 561..575 only (skip t = 576)
  if (w == 7) {
    const int tb   = 561;
    const int tml  = tb - l - 1;
    const int tb64 = tb - 64;
    const float4* rpq = (const float4*)(&ring[6][0]);
    const int rb = 4 * (35 & 3);
    const float4 rg0 = rpq[rb], rg1 = rpq[rb+1], rg2 = rpq[rb+2], rg3 = rpq[rb+3];
    DPSTEP(0,  cur0.x, 0, rg0.x, true) DPSTEP(1,  cur0.x, 1, rg0.y, true)
    DPSTEP(2,  cur0.y, 0, rg0.z, true) DPSTEP(3,  cur0.y, 1, rg0.w, true)
    DPSTEP(4,  cur1.x, 0, rg1.x, true) DPSTEP(5,  cur1.x, 1, rg1.y, true)
    DPSTEP(6,  cur1.y, 0, rg1.z, true) DPSTEP(7,  cur1.y, 1, rg1.w, true)
    DPSTEP(8,  cur2.x, 0, rg2.x, true) DPSTEP(9,  cur2.x, 1, rg2.y, true)
    DPSTEP(10, cur2.y, 0, rg2.z, true) DPSTEP(11, cur2.y, 1, rg2.w, true)
    DPSTEP(12, cur3.x, 0, rg3.x, true) DPSTEP(13, cur3.x, 1, rg3.y, true)
    DPSTEP(14, cur3.y, 0, rg3.z, true)
  }
#undef DP16
#undef DPSTEP

  if (tid == 511) out[b] = P * LN2f;   // P = r'(512,512) in log2 units
}

extern "C" void kernel_launch(void* const* d_in, const int* in_sizes, int n_in,
                              void* d_out, int out_size, void* d_ws, size_t ws_size,
                              hipStream_t stream)
{
  const float* x = (const float*)d_in[0];
  const float* y = (const float*)d_in[1];
  float* o = (float*)d_out;
  const size_t need = (size_t)64 * 512 * 516 * 2;   // 33,816,576 B
  if (ws_size >= need) {
    unsigned short* nd = (unsigned short*)d_ws;
    dist_kernel<<<dim3(64, 8), 256, 0, stream>>>(x, y, nd);
    dp_kernel<true><<<64, 512, 0, stream>>>(nd, x, y, o);
  } else {
    dp_kernel<false><<<64, 512, 0, stream>>>(nullptr, x, y, o);
  }
}